// Round 1
// baseline (200.062 us; speedup 1.0000x reference)
//
#include <hip/hip_runtime.h>

#define B_ 4
#define NTOK 2048
#define CCH 256
#define HH 8
#define DH 32
#define MM 64
#define DV 48           // 32 v + 8 cor_embed + 1 ones + 7 zero pad
#define ROWS (B_*NTOK)  // 8192

typedef __bf16 bf16_t;
typedef bf16_t bf16x8 __attribute__((ext_vector_type(8)));
typedef float f32x4 __attribute__((ext_vector_type(4)));
typedef unsigned int u32x2 __attribute__((ext_vector_type(2)));
typedef unsigned short u16;
typedef u16 u16x8 __attribute__((ext_vector_type(8)));

// fold softmax scale (Dh^-0.5) and log2(e) into Q so P = exp2(S') = exp(S*scale)
#define QSCALE (0.17677669529663687f * 1.44269504088896340f)

__device__ __forceinline__ u16 f2bf(float x) {
    unsigned u = __builtin_bit_cast(unsigned, x);
    return (u16)((u + 0x7FFFu + ((u >> 16) & 1u)) >> 16);  // RNE
}
__device__ __forceinline__ f32x4 mfma16(bf16x8 a, bf16x8 b, f32x4 c) {
    return __builtin_amdgcn_mfma_f32_16x16x32_bf16(a, b, c, 0, 0, 0);
}
#if __has_builtin(__builtin_amdgcn_exp2f)
#define EXP2(x) __builtin_amdgcn_exp2f(x)
#else
#define EXP2(x) exp2f(x)
#endif

// ---- convert + transpose weights: Wt[n][k] = bf16(W[k][n]) ----
__global__ void wcvt_k(const float* __restrict__ W, u16* __restrict__ Wt, int K, int N) {
    int i = blockIdx.x * 256 + threadIdx.x;
    if (i >= K * N) return;
    int k = i / N, n = i - k * N;           // read coalesced
    Wt[(size_t)n * K + k] = f2bf(W[i]);
}

// ---- cor_embed_ = cor @ Wcor  (f32, [ROWS][64]) ----
__global__ void ce_k(const float* __restrict__ cor, const float* __restrict__ Wcor,
                     float* __restrict__ ce) {
    int i = blockIdx.x * 256 + threadIdx.x;   // ROWS*64 threads
    int m = i & 63, bn = i >> 6;
    float v = cor[bn * 3 + 0] * Wcor[m] + cor[bn * 3 + 1] * Wcor[64 + m] +
              cor[bn * 3 + 2] * Wcor[128 + m];
    ce[i] = v;
}

// ---- fill Vt rows 32..47: cor_embed (bf16, transposed), ones row 40, zeros 41..47 ----
__global__ void vtfill_k(const float* __restrict__ ce, u16* __restrict__ Vt) {
    int bh = blockIdx.x >> 4;         // 0..31
    int rloc = blockIdx.x & 15;       // Vt row 32+rloc
    int b = bh >> 3, h = bh & 7;
    size_t vbase = ((size_t)bh * DV + 32 + rloc) * NTOK;
    for (int n = threadIdx.x; n < NTOK; n += 256) {
        u16 val;
        if (rloc < 8) val = f2bf(ce[((size_t)(b * NTOK + n)) * MM + h * 8 + rloc]);
        else          val = (rloc == 8) ? (u16)0x3F80 : (u16)0;   // 1.0 / 0.0
        Vt[vbase + n] = val;
    }
}

// ---- generic bf16-MFMA GEMM [8192,256] @ Bt[Nout][256]^T, mode-specific epilogue ----
// MODE 0: q proj -> Qh[b][h][n][32] bf16, scaled by QSCALE
// MODE 1: kv proj -> Kh[b][h][n][32] bf16 (c<256); Vt[b][h][dh][n] bf16 (c>=256)
// MODE 2: out proj (bf16 A) -> o_x[row][256] f32 + bias
template <int MODE>
__global__ __launch_bounds__(256) void gemm_k(
    const float* __restrict__ Af, const u16* __restrict__ Ab,
    const u16* __restrict__ Bt,
    u16* __restrict__ o_qk, u16* __restrict__ o_vt,
    float* __restrict__ o_x, const float* __restrict__ bias) {
    int lane = threadIdx.x & 63, wave = threadIdx.x >> 6;
    int g = lane >> 4, q = lane & 15;
    int m0 = blockIdx.x * 64 + wave * 16;
    int c0 = blockIdx.y * 64;
    f32x4 acc[4] = {};
#pragma unroll
    for (int k0 = 0; k0 < CCH; k0 += 32) {
        bf16x8 af;
        if (MODE == 2) {
            af = *(const bf16x8*)(Ab + (size_t)(m0 + q) * CCH + k0 + g * 8);
        } else {
            const float* ap = Af + (size_t)(m0 + q) * CCH + k0 + g * 8;
            f32x4 a0 = *(const f32x4*)ap;
            f32x4 a1 = *(const f32x4*)(ap + 4);
            u16x8 tv;
            tv[0] = f2bf(a0[0]); tv[1] = f2bf(a0[1]); tv[2] = f2bf(a0[2]); tv[3] = f2bf(a0[3]);
            tv[4] = f2bf(a1[0]); tv[5] = f2bf(a1[1]); tv[6] = f2bf(a1[2]); tv[7] = f2bf(a1[3]);
            af = __builtin_bit_cast(bf16x8, tv);
        }
#pragma unroll
        for (int t = 0; t < 4; t++) {
            bf16x8 bfr = *(const bf16x8*)(Bt + (size_t)(c0 + t * 16 + q) * CCH + k0 + g * 8);
            acc[t] = mfma16(af, bfr, acc[t]);
        }
    }
#pragma unroll
    for (int t = 0; t < 4; t++) {
#pragma unroll
        for (int r = 0; r < 4; r++) {
            int row = m0 + 4 * g + r;
            int c = c0 + t * 16 + q;
            float v = acc[t][r];
            int b = row >> 11, n = row & 2047;
            if (MODE == 0) {
                o_qk[((size_t)(b * HH + (c >> 5)) * NTOK + n) * DH + (c & 31)] = f2bf(v * QSCALE);
            } else if (MODE == 1) {
                if (c < 256) {
                    o_qk[((size_t)(b * HH + (c >> 5)) * NTOK + n) * DH + (c & 31)] = f2bf(v);
                } else {
                    int cc = c - 256;
                    o_vt[((size_t)(b * HH + (cc >> 5)) * DV + (cc & 31)) * NTOK + n] = f2bf(v);
                }
            } else {
                o_x[(size_t)row * CCH + c] = v + bias[c];
            }
        }
    }
}

// ---- fused attention: softmax(Q Kt) @ [V | CE | 1], per (b,h), 64 q-rows/block ----
__global__ __launch_bounds__(256) void attn_k(
    const u16* __restrict__ Qh, const u16* __restrict__ Kh, const u16* __restrict__ Vt,
    u16* __restrict__ xpre, float* __restrict__ cr) {
    __shared__ __align__(16) u16 Pl[4][16][40];   // per-wave P re-layout buffer (80B rows)
    int bh = blockIdx.y;
    int b = bh >> 3, h = bh & 7;
    int wave = threadIdx.x >> 6, lane = threadIdx.x & 63;
    int g = lane >> 4, q = lane & 15;
    int qbase = blockIdx.x * 64 + wave * 16;

    // Q B-fragment: lane holds Q[qbase+q][8g..8g+7]  (held for whole kernel)
    const u16* Qp = Qh + ((size_t)bh * NTOK + qbase + q) * DH + g * 8;
    bf16x8 qf = *(const bf16x8*)Qp;

    const u16* Kb = Kh + (size_t)bh * NTOK * DH;
    const u16* Vb = Vt + (size_t)bh * DV * NTOK;

    f32x4 acc[3] = {};
    const f32x4 zacc = {0.f, 0.f, 0.f, 0.f};
    u16* prow = &Pl[wave][q][0];

    for (int k0 = 0; k0 < NTOK; k0 += 32) {
        // S^T tiles: D = K_tile(16x32) . Q_tile^T -> lane holds S^T[key=4g+r][q]
        const u16* kp = Kb + (size_t)(k0 + q) * DH + g * 8;
        bf16x8 kf0 = *(const bf16x8*)kp;
        bf16x8 kf1 = *(const bf16x8*)(kp + 16 * DH);
        f32x4 s0 = mfma16(kf0, qf, zacc);
        f32x4 s1 = mfma16(kf1, qf, zacc);
        // P = exp2(S'), pack to bf16, write P[q][key] rows into LDS
        u32x2 w0, w1;
        w0[0] = (unsigned)f2bf(EXP2(s0[0])) | ((unsigned)f2bf(EXP2(s0[1])) << 16);
        w0[1] = (unsigned)f2bf(EXP2(s0[2])) | ((unsigned)f2bf(EXP2(s0[3])) << 16);
        w1[0] = (unsigned)f2bf(EXP2(s1[0])) | ((unsigned)f2bf(EXP2(s1[1])) << 16);
        w1[1] = (unsigned)f2bf(EXP2(s1[2])) | ((unsigned)f2bf(EXP2(s1[3])) << 16);
        *(u32x2*)(prow + g * 4) = w0;          // keys 4g..4g+3
        *(u32x2*)(prow + 16 + g * 4) = w1;     // keys 16+4g..16+4g+3
        // PV A-fragment: lane reads P[q][8g..8g+7] (wave-synchronous LDS round-trip)
        bf16x8 pf = *(const bf16x8*)(prow + g * 8);
#pragma unroll
        for (int t = 0; t < 3; t++) {
            bf16x8 vf = *(const bf16x8*)(Vb + (size_t)(t * 16 + q) * NTOK + k0 + g * 8);
            acc[t] = mfma16(pf, vf, acc[t]);
        }
    }

    // denominator sits at dv=40 -> tile 2, col 8 (ones row of Vt)
    float inv[4];
#pragma unroll
    for (int r = 0; r < 4; r++) {
        float den = __shfl(acc[2][r], (lane & 48) | 8, 64);
        inv[r] = 1.0f / den;
    }
#pragma unroll
    for (int r = 0; r < 4; r++) {
        size_t nrow = (size_t)b * NTOK + qbase + 4 * g + r;
        u16* xp = xpre + nrow * CCH + h * DH;
        xp[q] = f2bf(acc[0][r] * inv[r]);
        xp[16 + q] = f2bf(acc[1][r] * inv[r]);
        if (q < 8) cr[nrow * MM + h * 8 + q] = acc[2][r] * inv[r];
    }
}

// ---- motion = (cr - ce) @ Wm + bm ----
__global__ __launch_bounds__(256) void motion_k(
    const float* __restrict__ cr, const float* __restrict__ ce,
    const float* __restrict__ Wm, const float* __restrict__ bm,
    float* __restrict__ out) {
    __shared__ float diff[4][64];
    __shared__ float wm[64][64];
    int tid = threadIdx.x;
    int row0 = blockIdx.x * 4;
    for (int i = tid; i < 4096; i += 256) wm[i >> 6][i & 63] = Wm[i];
    {
        int rl = tid >> 6, k = tid & 63;
        size_t idx = (size_t)(row0 + rl) * 64 + k;
        diff[rl][k] = cr[idx] - ce[idx];
    }
    __syncthreads();
    int m = tid & 63, rl = tid >> 6;
    float v = bm[m];
#pragma unroll
    for (int k = 0; k < 64; k++) v += diff[rl][k] * wm[k][m];
    out[(size_t)(row0 + rl) * 64 + m] = v;
}

extern "C" void kernel_launch(void* const* d_in, const int* in_sizes, int n_in,
                              void* d_out, int out_size, void* d_ws, size_t ws_size,
                              hipStream_t stream) {
    const float* x1    = (const float*)d_in[0];
    const float* x2    = (const float*)d_in[1];
    const float* cor   = (const float*)d_in[2];
    const float* Wq    = (const float*)d_in[3];
    const float* Wkv   = (const float*)d_in[4];
    const float* Wcor  = (const float*)d_in[5];
    const float* Wproj = (const float*)d_in[6];
    const float* bproj = (const float*)d_in[7];
    const float* Wm    = (const float*)d_in[8];
    const float* bm    = (const float*)d_in[9];
    float* out_x = (float*)d_out;                          // [ROWS][256]
    float* out_motion = out_x + (size_t)ROWS * CCH;        // [ROWS][64]

    u16* Wqt   = (u16*)d_ws;                               // [256][256]
    u16* Wkvt  = Wqt + 256 * 256;                          // [512][256]
    u16* Wprojt= Wkvt + 512 * 256;                         // [256][256]
    u16* Qh    = Wprojt + 256 * 256;                       // [B*H][N][32]
    u16* Kh    = Qh + (size_t)B_ * HH * NTOK * DH;
    u16* Vt    = Kh + (size_t)B_ * HH * NTOK * DH;         // [B*H][48][N]
    u16* xpre  = Vt + (size_t)B_ * HH * DV * NTOK;         // [ROWS][256]
    float* cef = (float*)(xpre + (size_t)ROWS * CCH);      // [ROWS][64]
    float* crf = cef + (size_t)ROWS * MM;                  // [ROWS][64]
    // total ws use: ~22.5 MB

    wcvt_k<<<(256 * 256 + 255) / 256, 256, 0, stream>>>(Wq, Wqt, 256, 256);
    wcvt_k<<<(256 * 512 + 255) / 256, 256, 0, stream>>>(Wkv, Wkvt, 256, 512);
    wcvt_k<<<(256 * 256 + 255) / 256, 256, 0, stream>>>(Wproj, Wprojt, 256, 256);
    ce_k<<<ROWS * MM / 256, 256, 0, stream>>>(cor, Wcor, cef);
    vtfill_k<<<32 * 16, 256, 0, stream>>>(cef, Vt);
    gemm_k<0><<<dim3(128, 4), 256, 0, stream>>>(x1, nullptr, Wqt, Qh, nullptr, nullptr, nullptr);
    gemm_k<1><<<dim3(128, 8), 256, 0, stream>>>(x2, nullptr, Wkvt, Kh, Vt, nullptr, nullptr);
    attn_k<<<dim3(32, 32), 256, 0, stream>>>(Qh, Kh, Vt, xpre, crf);
    gemm_k<2><<<dim3(128, 4), 256, 0, stream>>>(nullptr, xpre, Wprojt, nullptr, nullptr, out_x, bproj);
    motion_k<<<ROWS / 4, 256, 0, stream>>>(crf, cef, Wm, bm, out_motion);
}

// Round 2
// 143.513 us; speedup vs baseline: 1.3940x; 1.3940x over previous
//
#include <hip/hip_runtime.h>

#define B_ 4
#define NTOK 2048
#define CCH 256
#define HH 8
#define DH 32
#define MM 64
#define DV 48           // 32 v + 8 cor_embed + 1 ones + 7 zero pad
#define ROWS (B_*NTOK)  // 8192

typedef __bf16 bf16_t;
typedef bf16_t bf16x8 __attribute__((ext_vector_type(8)));
typedef float f32x4 __attribute__((ext_vector_type(4)));
typedef unsigned int u32x2 __attribute__((ext_vector_type(2)));
typedef unsigned int u32x4 __attribute__((ext_vector_type(4)));
typedef unsigned short u16;
typedef u16 u16x8 __attribute__((ext_vector_type(8)));

// fold softmax scale (Dh^-0.5) and log2(e) into Q so P = exp2(S') = exp(S*scale)
#define QSCALE (0.17677669529663687f * 1.44269504088896340f)

__device__ __forceinline__ u16 f2bf(float x) {
    unsigned u = __builtin_bit_cast(unsigned, x);
    return (u16)((u + 0x7FFFu + ((u >> 16) & 1u)) >> 16);  // RNE
}
// packed f32x2 -> bf16x2 (lo = src0, hi = src1), single VALU op (T12)
__device__ __forceinline__ unsigned cvt_pk(float lo, float hi) {
    unsigned r;
    asm("v_cvt_pk_bf16_f32 %0, %1, %2" : "=v"(r) : "v"(lo), "v"(hi));
    return r;
}
__device__ __forceinline__ f32x4 mfma16(bf16x8 a, bf16x8 b, f32x4 c) {
    return __builtin_amdgcn_mfma_f32_16x16x32_bf16(a, b, c, 0, 0, 0);
}
#if __has_builtin(__builtin_amdgcn_exp2f)
#define EXP2(x) __builtin_amdgcn_exp2f(x)
#else
#define EXP2(x) exp2f(x)
#endif

// ---- convert fp32 activations to bf16 rows (vectorized, cvt_pk) ----
__global__ void xcvt_k(const float* __restrict__ X, u16* __restrict__ Xb) {
    int i = blockIdx.x * 256 + threadIdx.x;   // one thread per 8 elements
    f32x4 a0 = *(const f32x4*)(X + (size_t)i * 8);
    f32x4 a1 = *(const f32x4*)(X + (size_t)i * 8 + 4);
    u32x4 w;
    w[0] = cvt_pk(a0[0], a0[1]);
    w[1] = cvt_pk(a0[2], a0[3]);
    w[2] = cvt_pk(a1[0], a1[1]);
    w[3] = cvt_pk(a1[2], a1[3]);
    *(u32x4*)(Xb + (size_t)i * 8) = w;
}

// ---- convert + transpose weights: Wt[n][k] = bf16(W[k][n]) ----
__global__ void wcvt_k(const float* __restrict__ W, u16* __restrict__ Wt, int K, int N) {
    int i = blockIdx.x * 256 + threadIdx.x;
    if (i >= K * N) return;
    int k = i / N, n = i - k * N;           // read coalesced
    Wt[(size_t)n * K + k] = f2bf(W[i]);
}

// ---- cor_embed_ = cor @ Wcor  (f32, [ROWS][64]) ----
__global__ void ce_k(const float* __restrict__ cor, const float* __restrict__ Wcor,
                     float* __restrict__ ce) {
    int i = blockIdx.x * 256 + threadIdx.x;   // ROWS*64 threads
    int m = i & 63, bn = i >> 6;
    float v = cor[bn * 3 + 0] * Wcor[m] + cor[bn * 3 + 1] * Wcor[64 + m] +
              cor[bn * 3 + 2] * Wcor[128 + m];
    ce[i] = v;
}

// ---- fill Vt rows 32..47: cor_embed (bf16, transposed), ones row 40, zeros 41..47 ----
__global__ void vtfill_k(const float* __restrict__ ce, u16* __restrict__ Vt) {
    int bh = blockIdx.x >> 4;         // 0..31
    int rloc = blockIdx.x & 15;       // Vt row 32+rloc
    int b = bh >> 3, h = bh & 7;
    size_t vbase = ((size_t)bh * DV + 32 + rloc) * NTOK;
    for (int n = threadIdx.x; n < NTOK; n += 256) {
        u16 val;
        if (rloc < 8) val = f2bf(ce[((size_t)(b * NTOK + n)) * MM + h * 8 + rloc]);
        else          val = (rloc == 8) ? (u16)0x3F80 : (u16)0;   // 1.0 / 0.0
        Vt[vbase + n] = val;
    }
}

// ---- bf16-MFMA GEMM A[8192,256](bf16) @ Bt[Nout][256]^T, mode-specific epilogue ----
// MODE 0: q proj -> Qh[b][h][n][32] bf16, scaled by QSCALE
// MODE 1: kv proj -> Kh[b][h][n][32] bf16 (c<256); Vt[b][h][dh][n] bf16 (c>=256)
// MODE 2: out proj -> o_x[row][256] f32 + bias
template <int MODE>
__global__ __launch_bounds__(256) void gemm_k(
    const u16* __restrict__ Ab, const u16* __restrict__ Bt,
    u16* __restrict__ o_qk, u16* __restrict__ o_vt,
    float* __restrict__ o_x, const float* __restrict__ bias) {
    int lane = threadIdx.x & 63, wave = threadIdx.x >> 6;
    int g = lane >> 4, q = lane & 15;
    int m0 = blockIdx.x * 64 + wave * 16;
    int c0 = blockIdx.y * 64;
    f32x4 acc[4] = {};
#pragma unroll
    for (int k0 = 0; k0 < CCH; k0 += 32) {
        bf16x8 af = *(const bf16x8*)(Ab + (size_t)(m0 + q) * CCH + k0 + g * 8);
#pragma unroll
        for (int t = 0; t < 4; t++) {
            bf16x8 bfr = *(const bf16x8*)(Bt + (size_t)(c0 + t * 16 + q) * CCH + k0 + g * 8);
            acc[t] = mfma16(af, bfr, acc[t]);
        }
    }
#pragma unroll
    for (int t = 0; t < 4; t++) {
#pragma unroll
        for (int r = 0; r < 4; r++) {
            int row = m0 + 4 * g + r;
            int c = c0 + t * 16 + q;
            float v = acc[t][r];
            int b = row >> 11, n = row & 2047;
            if (MODE == 0) {
                o_qk[((size_t)(b * HH + (c >> 5)) * NTOK + n) * DH + (c & 31)] = f2bf(v * QSCALE);
            } else if (MODE == 1) {
                if (c < 256) {
                    o_qk[((size_t)(b * HH + (c >> 5)) * NTOK + n) * DH + (c & 31)] = f2bf(v);
                } else {
                    int cc = c - 256;
                    o_vt[((size_t)(b * HH + (cc >> 5)) * DV + (cc & 31)) * NTOK + n] = f2bf(v);
                }
            } else {
                o_x[(size_t)row * CCH + c] = v + bias[c];
            }
        }
    }
}

// ---- fused attention: softmax(Q Kt) @ [V | CE | 1], per (b,h), 32 q-rows/wave ----
__global__ __launch_bounds__(256) void attn_k(
    const u16* __restrict__ Qh, const u16* __restrict__ Kh, const u16* __restrict__ Vt,
    u16* __restrict__ xpre, float* __restrict__ cr) {
    // P re-layout buffer: [wave][qtile][q-row][20 u32]  (80B row stride: 16B-aligned
    // b128 reads land on distinct 4-bank groups; b64 writes 2-way = free)
    __shared__ __align__(16) unsigned Pl[4][2][16][20];
    int bh = blockIdx.y;
    int b = bh >> 3, h = bh & 7;
    int wave = threadIdx.x >> 6, lane = threadIdx.x & 63;
    int g = lane >> 4, q = lane & 15;
    int qbase = blockIdx.x * 128 + wave * 32;

    // Q B-fragments for 2 q-tiles (held in regs for whole kernel)
    const u16* Qp = Qh + ((size_t)bh * NTOK + qbase + q) * DH + g * 8;
    bf16x8 qf0 = *(const bf16x8*)Qp;
    bf16x8 qf1 = *(const bf16x8*)(Qp + 16 * DH);

    const u16* Kb = Kh + (size_t)bh * NTOK * DH + (size_t)q * DH + g * 8;
    const u16* Vb = Vt + (size_t)bh * DV * NTOK + (size_t)q * NTOK + g * 8;

    f32x4 acc[2][3] = {};
    const f32x4 zacc = {0.f, 0.f, 0.f, 0.f};
    unsigned* p0 = &Pl[wave][0][q][0];
    unsigned* p1 = &Pl[wave][1][q][0];

    // prefetch k-tile 0
    bf16x8 ka = *(const bf16x8*)(Kb);
    bf16x8 kb = *(const bf16x8*)(Kb + 16 * DH);
    bf16x8 va = *(const bf16x8*)(Vb);
    bf16x8 vb = *(const bf16x8*)(Vb + 16 * NTOK);
    bf16x8 vc = *(const bf16x8*)(Vb + 32 * NTOK);

#pragma unroll 2
    for (int k0 = 0; k0 < NTOK; k0 += 32) {
        // issue next k-tile's loads first (latency hides under exp/LDS chain)
        int kn = (k0 + 32) & (NTOK - 1);       // wraps on last iter: harmless reload
        bf16x8 kan = *(const bf16x8*)(Kb + (size_t)kn * DH);
        bf16x8 kbn = *(const bf16x8*)(Kb + (size_t)(kn + 16) * DH);
        bf16x8 van = *(const bf16x8*)(Vb + kn);
        bf16x8 vbn = *(const bf16x8*)(Vb + 16 * NTOK + kn);
        bf16x8 vcn = *(const bf16x8*)(Vb + 32 * NTOK + kn);

        // S^T tiles: lane(g,q) reg r = S^T[key kt*16+4g+r][qtile q-col]
        f32x4 s00 = mfma16(ka, qf0, zacc);
        f32x4 s10 = mfma16(kb, qf0, zacc);
        f32x4 s01 = mfma16(ka, qf1, zacc);
        f32x4 s11 = mfma16(kb, qf1, zacc);

        // P = exp2(S'), pack pairs with v_cvt_pk_bf16_f32, scatter rows to LDS
        u32x2 w;
        w[0] = cvt_pk(EXP2(s00[0]), EXP2(s00[1]));
        w[1] = cvt_pk(EXP2(s00[2]), EXP2(s00[3]));
        *(u32x2*)(p0 + 2 * g) = w;             // qt0 keys 4g..4g+3
        w[0] = cvt_pk(EXP2(s10[0]), EXP2(s10[1]));
        w[1] = cvt_pk(EXP2(s10[2]), EXP2(s10[3]));
        *(u32x2*)(p0 + 8 + 2 * g) = w;         // qt0 keys 16+4g..
        w[0] = cvt_pk(EXP2(s01[0]), EXP2(s01[1]));
        w[1] = cvt_pk(EXP2(s01[2]), EXP2(s01[3]));
        *(u32x2*)(p1 + 2 * g) = w;
        w[0] = cvt_pk(EXP2(s11[0]), EXP2(s11[1]));
        w[1] = cvt_pk(EXP2(s11[2]), EXP2(s11[3]));
        *(u32x2*)(p1 + 8 + 2 * g) = w;

        // PV A-fragments: lane(g,q) = P[q][keys 8g..8g+7] (wave-synchronous)
        bf16x8 pf0 = *(const bf16x8*)(p0 + 4 * g);
        bf16x8 pf1 = *(const bf16x8*)(p1 + 4 * g);
        acc[0][0] = mfma16(pf0, va, acc[0][0]);
        acc[1][0] = mfma16(pf1, va, acc[1][0]);
        acc[0][1] = mfma16(pf0, vb, acc[0][1]);
        acc[1][1] = mfma16(pf1, vb, acc[1][1]);
        acc[0][2] = mfma16(pf0, vc, acc[0][2]);
        acc[1][2] = mfma16(pf1, vc, acc[1][2]);

        ka = kan; kb = kbn; va = van; vb = vbn; vc = vcn;
    }

    // denominator = ones-row of Vt at dv=40 -> tile 2, col 8
#pragma unroll
    for (int qt = 0; qt < 2; qt++) {
        float inv[4];
#pragma unroll
        for (int r = 0; r < 4; r++) {
            float den = __shfl(acc[qt][2][r], (lane & 48) | 8, 64);
            inv[r] = 1.0f / den;
        }
#pragma unroll
        for (int r = 0; r < 4; r++) {
            size_t nrow = (size_t)b * NTOK + qbase + qt * 16 + 4 * g + r;
            u16* xp = xpre + nrow * CCH + h * DH;
            xp[q] = f2bf(acc[qt][0][r] * inv[r]);
            xp[16 + q] = f2bf(acc[qt][1][r] * inv[r]);
            if (q < 8) cr[nrow * MM + h * 8 + q] = acc[qt][2][r] * inv[r];
        }
    }
}

// ---- motion = (cr - ce) @ Wm + bm ----
__global__ __launch_bounds__(256) void motion_k(
    const float* __restrict__ cr, const float* __restrict__ ce,
    const float* __restrict__ Wm, const float* __restrict__ bm,
    float* __restrict__ out) {
    __shared__ float diff[4][64];
    __shared__ float wm[64][64];
    int tid = threadIdx.x;
    int row0 = blockIdx.x * 4;
    for (int i = tid; i < 4096; i += 256) wm[i >> 6][i & 63] = Wm[i];
    {
        int rl = tid >> 6, k = tid & 63;
        size_t idx = (size_t)(row0 + rl) * 64 + k;
        diff[rl][k] = cr[idx] - ce[idx];
    }
    __syncthreads();
    int m = tid & 63, rl = tid >> 6;
    float v = bm[m];
#pragma unroll
    for (int k = 0; k < 64; k++) v += diff[rl][k] * wm[k][m];
    out[(size_t)(row0 + rl) * 64 + m] = v;
}

extern "C" void kernel_launch(void* const* d_in, const int* in_sizes, int n_in,
                              void* d_out, int out_size, void* d_ws, size_t ws_size,
                              hipStream_t stream) {
    const float* x1    = (const float*)d_in[0];
    const float* x2    = (const float*)d_in[1];
    const float* cor   = (const float*)d_in[2];
    const float* Wq    = (const float*)d_in[3];
    const float* Wkv   = (const float*)d_in[4];
    const float* Wcor  = (const float*)d_in[5];
    const float* Wproj = (const float*)d_in[6];
    const float* bproj = (const float*)d_in[7];
    const float* Wm    = (const float*)d_in[8];
    const float* bm    = (const float*)d_in[9];
    float* out_x = (float*)d_out;                          // [ROWS][256]
    float* out_motion = out_x + (size_t)ROWS * CCH;        // [ROWS][64]

    u16* Wqt   = (u16*)d_ws;                               // [256][256]
    u16* Wkvt  = Wqt + 256 * 256;                          // [512][256]
    u16* Wprojt= Wkvt + 512 * 256;                         // [256][256]
    u16* x1b   = Wprojt + 256 * 256;                       // [ROWS][256] bf16
    u16* x2b   = x1b + (size_t)ROWS * CCH;
    u16* Qh    = x2b + (size_t)ROWS * CCH;                 // [B*H][N][32]
    u16* Kh    = Qh + (size_t)B_ * HH * NTOK * DH;
    u16* Vt    = Kh + (size_t)B_ * HH * NTOK * DH;         // [B*H][48][N]
    u16* xpre  = Vt + (size_t)B_ * HH * DV * NTOK;         // [ROWS][256]
    float* cef = (float*)(xpre + (size_t)ROWS * CCH);      // [ROWS][64]
    float* crf = cef + (size_t)ROWS * MM;                  // [ROWS][64]
    // total ws use: ~31 MB

    xcvt_k<<<ROWS * CCH / 8 / 256, 256, 0, stream>>>(x1, x1b);
    xcvt_k<<<ROWS * CCH / 8 / 256, 256, 0, stream>>>(x2, x2b);
    wcvt_k<<<(256 * 256 + 255) / 256, 256, 0, stream>>>(Wq, Wqt, 256, 256);
    wcvt_k<<<(256 * 512 + 255) / 256, 256, 0, stream>>>(Wkv, Wkvt, 256, 512);
    wcvt_k<<<(256 * 256 + 255) / 256, 256, 0, stream>>>(Wproj, Wprojt, 256, 256);
    ce_k<<<ROWS * MM / 256, 256, 0, stream>>>(cor, Wcor, cef);
    vtfill_k<<<32 * 16, 256, 0, stream>>>(cef, Vt);
    gemm_k<0><<<dim3(128, 4), 256, 0, stream>>>(x1b, Wqt, Qh, nullptr, nullptr, nullptr);
    gemm_k<1><<<dim3(128, 8), 256, 0, stream>>>(x2b, Wkvt, Kh, Vt, nullptr, nullptr);
    attn_k<<<dim3(16, 32), 256, 0, stream>>>(Qh, Kh, Vt, xpre, crf);
    gemm_k<2><<<dim3(128, 4), 256, 0, stream>>>(xpre, Wprojt, nullptr, nullptr, out_x, bproj);
    motion_k<<<ROWS / 4, 256, 0, stream>>>(crf, cef, Wm, bm, out_motion);
}

// Round 3
// 125.438 us; speedup vs baseline: 1.5949x; 1.1441x over previous
//
#include <hip/hip_runtime.h>

#define B_ 4
#define NTOK 2048
#define CCH 256
#define HH 8
#define DH 32
#define MM 64
#define DV 48           // 32 v + 3 corT + 1 ones + 12 junk (never read)
#define ROWS (B_*NTOK)  // 8192

typedef __bf16 bf16_t;
typedef bf16_t bf16x8 __attribute__((ext_vector_type(8)));
typedef float f32x4 __attribute__((ext_vector_type(4)));
typedef unsigned int u32x4 __attribute__((ext_vector_type(4)));
typedef unsigned short u16;

// fold softmax scale (Dh^-0.5) and log2(e) into Q so P = exp2(S') = exp(S*scale)
#define QSCALE (0.17677669529663687f * 1.44269504088896340f)

__device__ __forceinline__ u16 f2bf(float x) {
    unsigned u = __builtin_bit_cast(unsigned, x);
    return (u16)((u + 0x7FFFu + ((u >> 16) & 1u)) >> 16);  // RNE
}
__device__ __forceinline__ unsigned cvt_pk(float lo, float hi) {
    unsigned r;
    asm("v_cvt_pk_bf16_f32 %0, %1, %2" : "=v"(r) : "v"(lo), "v"(hi));
    return r;
}
__device__ __forceinline__ f32x4 mfma16(bf16x8 a, bf16x8 b, f32x4 c) {
    return __builtin_amdgcn_mfma_f32_16x16x32_bf16(a, b, c, 0, 0, 0);
}
#if __has_builtin(__builtin_amdgcn_exp2f)
#define EXP2(x) __builtin_amdgcn_exp2f(x)
#else
#define EXP2(x) exp2f(x)
#endif

// exp2 the 8 S^T values (2 tiles x 4 regs), pack to bf16, and transpose the
// 4x4 u32 block across lane groups {q, q+16, q+32, q+48} so the result is the
// PV A-fragment: lane(g,q) = P[row q][keys 8g..8g+7]. No LDS involved.
__device__ __forceinline__ bf16x8 exp_transpose(f32x4 s0, f32x4 s1) {
    unsigned W0 = cvt_pk(EXP2(s0[0]), EXP2(s0[1]));   // keys 4g+0,4g+1
    unsigned W1 = cvt_pk(EXP2(s0[2]), EXP2(s0[3]));   // keys 4g+2,4g+3
    unsigned W2 = cvt_pk(EXP2(s1[0]), EXP2(s1[1]));   // keys 16+4g+0,+1
    unsigned W3 = cvt_pk(EXP2(s1[2]), EXP2(s1[3]));   // keys 16+4g+2,+3
    asm("v_permlane32_swap_b32 %0, %1" : "+v"(W0), "+v"(W2));
    asm("v_permlane32_swap_b32 %0, %1" : "+v"(W1), "+v"(W3));
    asm("v_permlane16_swap_b32 %0, %1" : "+v"(W0), "+v"(W2));
    asm("v_permlane16_swap_b32 %0, %1" : "+v"(W1), "+v"(W3));
    u32x4 pw; pw[0] = W0; pw[1] = W1; pw[2] = W2; pw[3] = W3;
    return __builtin_bit_cast(bf16x8, pw);
}

// ---- fused prep: x1/x2 bf16 convert, weight transposes, corT+ones, G ----
__global__ __launch_bounds__(256) void prep_k(
    const float* __restrict__ x1, const float* __restrict__ x2,
    const float* __restrict__ Wq, const float* __restrict__ Wkv,
    const float* __restrict__ Wproj, const float* __restrict__ cor,
    const float* __restrict__ Wcor, const float* __restrict__ Wm,
    u16* __restrict__ x1b, u16* __restrict__ x2b,
    u16* __restrict__ Wqt, u16* __restrict__ Wkvt, u16* __restrict__ Wprojt,
    u16* __restrict__ Vt, float* __restrict__ G) {
    int bx = blockIdx.x, tid = threadIdx.x;
    if (bx < 2048) {                       // x1/x2 -> bf16, 8 elems/thread
        const float* X = (bx < 1024) ? x1 : x2;
        u16* Xb = (bx < 1024) ? x1b : x2b;
        size_t i = (size_t)(bx & 1023) * 256 + tid;
        f32x4 a0 = *(const f32x4*)(X + i * 8);
        f32x4 a1 = *(const f32x4*)(X + i * 8 + 4);
        u32x4 w;
        w[0] = cvt_pk(a0[0], a0[1]);
        w[1] = cvt_pk(a0[2], a0[3]);
        w[2] = cvt_pk(a1[0], a1[1]);
        w[3] = cvt_pk(a1[2], a1[3]);
        *(u32x4*)(Xb + i * 8) = w;
    } else if (bx < 3072) {                // weight transpose-converts
        int r = bx - 2048;
        const float* W; u16* Wt; int N, base;
        if (r < 256)      { W = Wq;    Wt = Wqt;    N = 256; base = r; }
        else if (r < 768) { W = Wkv;   Wt = Wkvt;   N = 512; base = r - 256; }
        else              { W = Wproj; Wt = Wprojt; N = 256; base = r - 768; }
        int i = base * 256 + tid;
        int k = i / N, n = i - k * N;      // read coalesced, write strided
        Wt[(size_t)n * 256 + k] = f2bf(W[i]);
    } else if (bx < 3104) {                // Vt rows 32..35: corT + ones
        int bh = bx - 3072;
        int b2 = bh >> 3;
        for (int n = tid; n < NTOK; n += 256) {
            const float* cp = cor + ((size_t)b2 * NTOK + n) * 3;
            u16* vp = Vt + ((size_t)bh * DV + 32) * NTOK + n;
            vp[0]        = f2bf(cp[0]);
            vp[NTOK]     = f2bf(cp[1]);
            vp[2 * NTOK] = f2bf(cp[2]);
            vp[3 * NTOK] = (u16)0x3F80;    // 1.0
        }
    } else {                               // G[h*3+j][m] = Wcor_blk @ Wm_blk
        int idx = (bx - 3104) * 256 + tid;    // < 1536
        int m = idx & 63, hj = idx >> 6;      // hj < 24
        int hh = hj / 3, j = hj - 3 * hh;
        float acc = 0.f;
#pragma unroll
        for (int t = 0; t < 8; t++)
            acc += Wcor[j * 64 + hh * 8 + t] * Wm[(hh * 8 + t) * 64 + m];
        G[idx] = acc;
    }
}

// ---- bf16-MFMA GEMM A[8192,256](bf16) @ Bt[Nout][256]^T, mode-specific epilogue ----
template <int MODE>
__global__ __launch_bounds__(256, 4) void gemm_k(
    const u16* __restrict__ Ab, const u16* __restrict__ Bt,
    u16* __restrict__ o_qk, u16* __restrict__ o_vt,
    float* __restrict__ o_x, const float* __restrict__ bias) {
    int lane = threadIdx.x & 63, wave = threadIdx.x >> 6;
    int g = lane >> 4, q = lane & 15;
    int m0 = blockIdx.x * 64 + wave * 16;
    int c0 = blockIdx.y * 64;
    f32x4 acc[4] = {};
#pragma unroll
    for (int k0 = 0; k0 < CCH; k0 += 32) {
        bf16x8 af = *(const bf16x8*)(Ab + (size_t)(m0 + q) * CCH + k0 + g * 8);
#pragma unroll
        for (int t = 0; t < 4; t++) {
            bf16x8 bfr = *(const bf16x8*)(Bt + (size_t)(c0 + t * 16 + q) * CCH + k0 + g * 8);
            acc[t] = mfma16(af, bfr, acc[t]);
        }
    }
#pragma unroll
    for (int t = 0; t < 4; t++) {
#pragma unroll
        for (int r = 0; r < 4; r++) {
            int row = m0 + 4 * g + r;
            int c = c0 + t * 16 + q;
            float v = acc[t][r];
            int b = row >> 11, n = row & 2047;
            if (MODE == 0) {
                o_qk[((size_t)(b * HH + (c >> 5)) * NTOK + n) * DH + (c & 31)] = f2bf(v * QSCALE);
            } else if (MODE == 1) {
                if (c < 256) {
                    o_qk[((size_t)(b * HH + (c >> 5)) * NTOK + n) * DH + (c & 31)] = f2bf(v);
                } else {
                    int cc = c - 256;
                    o_vt[((size_t)(b * HH + (cc >> 5)) * DV + (cc & 31)) * NTOK + n] = f2bf(v);
                }
            } else {
                o_x[(size_t)row * CCH + c] = v + bias[c];
            }
        }
    }
}

// one pipeline stage: load K(t+2) | S-MFMA(t+1) from set Y | exp/perm(t) | PV(t) on set X | load V(t+2)
#define ATTN_BODY(kaX, kbX, vaX, vbX, vcX, kaY, kbY, sX00, sX10, sX01, sX11, \
                  sY00, sY10, sY01, sY11)                                     \
    kaX = *(const bf16x8*)(kp);                                               \
    kbX = *(const bf16x8*)(kp + 16 * DH);                                     \
    kp += 32 * DH;                                                            \
    __builtin_amdgcn_s_setprio(1);                                            \
    sY00 = mfma16(kaY, qf0, zacc);                                            \
    sY10 = mfma16(kbY, qf0, zacc);                                            \
    sY01 = mfma16(kaY, qf1, zacc);                                            \
    sY11 = mfma16(kbY, qf1, zacc);                                            \
    __builtin_amdgcn_s_setprio(0);                                            \
    {                                                                         \
        bf16x8 pf0 = exp_transpose(sX00, sX10);                               \
        bf16x8 pf1 = exp_transpose(sX01, sX11);                               \
        __builtin_amdgcn_s_setprio(1);                                        \
        acc00 = mfma16(pf0, vaX, acc00);                                      \
        acc10 = mfma16(pf1, vaX, acc10);                                      \
        acc01 = mfma16(pf0, vbX, acc01);                                      \
        acc11 = mfma16(pf1, vbX, acc11);                                      \
        acc02 = mfma16(pf0, vcX, acc02);                                      \
        acc12 = mfma16(pf1, vcX, acc12);                                      \
        __builtin_amdgcn_s_setprio(0);                                        \
    }                                                                         \
    vaX = *(const bf16x8*)(Vb + voff);                                        \
    vbX = *(const bf16x8*)(Vb + 16 * NTOK + voff);                            \
    vcX = *(const bf16x8*)(Vb + 32 * NTOK + voff);                            \
    voff += 32;

// ---- fused attention: softmax(Q Kt) @ [V | corT | 1], 32 q-rows/wave, no LDS ----
__global__ __launch_bounds__(256, 2) void attn_k(
    const u16* __restrict__ Qh, const u16* __restrict__ Kh, const u16* __restrict__ Vt,
    u16* __restrict__ xpre, float* __restrict__ pc) {
    int bh = blockIdx.y;
    int b = bh >> 3, h = bh & 7;
    int wave = threadIdx.x >> 6, lane = threadIdx.x & 63;
    int g = lane >> 4, q = lane & 15;
    int qbase = blockIdx.x * 128 + wave * 32;

    const u16* Qp = Qh + ((size_t)bh * NTOK + qbase + q) * DH + g * 8;
    bf16x8 qf0 = *(const bf16x8*)Qp;
    bf16x8 qf1 = *(const bf16x8*)(Qp + 16 * DH);

    const u16* Kb = Kh + (size_t)bh * NTOK * DH + (size_t)q * DH + g * 8;
    const u16* Vb = Vt + (size_t)bh * DV * NTOK + (size_t)q * NTOK + g * 8;

    f32x4 acc00 = {}, acc01 = {}, acc02 = {}, acc10 = {}, acc11 = {}, acc12 = {};
    const f32x4 zacc = {0.f, 0.f, 0.f, 0.f};

    // prologue: tiles 0 (set A) and 1 (set B); S(0)
    bf16x8 kaA = *(const bf16x8*)(Kb);
    bf16x8 kbA = *(const bf16x8*)(Kb + 16 * DH);
    bf16x8 vaA = *(const bf16x8*)(Vb);
    bf16x8 vbA = *(const bf16x8*)(Vb + 16 * NTOK);
    bf16x8 vcA = *(const bf16x8*)(Vb + 32 * NTOK);
    bf16x8 kaB = *(const bf16x8*)(Kb + 32 * DH);
    bf16x8 kbB = *(const bf16x8*)(Kb + 48 * DH);
    bf16x8 vaB = *(const bf16x8*)(Vb + 32);
    bf16x8 vbB = *(const bf16x8*)(Vb + 16 * NTOK + 32);
    bf16x8 vcB = *(const bf16x8*)(Vb + 32 * NTOK + 32);

    f32x4 sA00 = mfma16(kaA, qf0, zacc);
    f32x4 sA10 = mfma16(kbA, qf0, zacc);
    f32x4 sA01 = mfma16(kaA, qf1, zacc);
    f32x4 sA11 = mfma16(kbA, qf1, zacc);
    f32x4 sB00, sB10, sB01, sB11;

    const u16* kp = Kb + 64 * DH;   // loads run 2 tiles ahead (overruns <=4KB into
    int voff = 64;                  // the next ws buffer on the last 2 iters: junk, unused)

#pragma unroll 1
    for (int tp = 0; tp < 32; tp++) {
        ATTN_BODY(kaA, kbA, vaA, vbA, vcA, kaB, kbB,
                  sA00, sA10, sA01, sA11, sB00, sB10, sB01, sB11)
        ATTN_BODY(kaB, kbB, vaB, vbB, vcB, kaA, kbA,
                  sB00, sB10, sB01, sB11, sA00, sA10, sA01, sA11)
    }

    // denominator = ones-row (dv 35 -> tile 2 col 3)
    float inv0[4], inv1[4];
#pragma unroll
    for (int r = 0; r < 4; r++) {
        inv0[r] = 1.0f / __shfl(acc02[r], (lane & 48) | 3, 64);
        inv1[r] = 1.0f / __shfl(acc12[r], (lane & 48) | 3, 64);
    }
#pragma unroll
    for (int r = 0; r < 4; r++) {
        size_t nrow0 = (size_t)b * NTOK + qbase + 4 * g + r;
        size_t nrow1 = nrow0 + 16;
        u16* xp0 = xpre + nrow0 * CCH + h * DH;
        u16* xp1 = xpre + nrow1 * CCH + h * DH;
        xp0[q] = f2bf(acc00[r] * inv0[r]);
        xp0[16 + q] = f2bf(acc01[r] * inv0[r]);
        xp1[q] = f2bf(acc10[r] * inv1[r]);
        xp1[16 + q] = f2bf(acc11[r] * inv1[r]);
        if (q < 3) {
            pc[nrow0 * 24 + h * 3 + q] = acc02[r] * inv0[r];
            pc[nrow1 * 24 + h * 3 + q] = acc12[r] * inv1[r];
        }
    }
}

// ---- motion[tok,m] = bm[m] + sum_{h,j} (pc[tok,h,j]-cor[tok,j]) * G[h*3+j][m] ----
__global__ __launch_bounds__(256) void motion_k(
    const float* __restrict__ pc, const float* __restrict__ cor,
    const float* __restrict__ G, const float* __restrict__ bm,
    float* __restrict__ out) {
    __shared__ float Gs[24][64];
    __shared__ float u[4][24];
    int tid = threadIdx.x;
    for (int i = tid; i < 1536; i += 256) Gs[i >> 6][i & 63] = G[i];
    int tok0 = blockIdx.x * 4;
    if (tid < 96) {
        int tl = tid / 24, e = tid - tl * 24;
        int j = e % 3;
        size_t token = tok0 + tl;
        u[tl][e] = pc[token * 24 + e] - cor[token * 3 + j];
    }
    __syncthreads();
    int tl = tid >> 6, m = tid & 63;
    float v = bm[m];
#pragma unroll
    for (int e = 0; e < 24; e++) v += u[tl][e] * Gs[e][m];
    out[(size_t)(tok0 + tl) * 64 + m] = v;
}

extern "C" void kernel_launch(void* const* d_in, const int* in_sizes, int n_in,
                              void* d_out, int out_size, void* d_ws, size_t ws_size,
                              hipStream_t stream) {
    const float* x1    = (const float*)d_in[0];
    const float* x2    = (const float*)d_in[1];
    const float* cor   = (const float*)d_in[2];
    const float* Wq    = (const float*)d_in[3];
    const float* Wkv   = (const float*)d_in[4];
    const float* Wcor  = (const float*)d_in[5];
    const float* Wproj = (const float*)d_in[6];
    const float* bproj = (const float*)d_in[7];
    const float* Wm    = (const float*)d_in[8];
    const float* bm    = (const float*)d_in[9];
    float* out_x = (float*)d_out;                          // [ROWS][256]
    float* out_motion = out_x + (size_t)ROWS * CCH;        // [ROWS][64]

    u16* Wqt    = (u16*)d_ws;                              // 65536
    u16* Wkvt   = Wqt + 65536;                             // 131072
    u16* Wprojt = Wkvt + 131072;                           // 65536
    u16* x1b    = Wprojt + 65536;                          // 2097152
    u16* x2b    = x1b + (size_t)2097152;
    u16* Qh     = x2b + (size_t)2097152;                   // [B*H][N][32]
    u16* Kh     = Qh + (size_t)2097152;
    u16* Vt     = Kh + (size_t)2097152;                    // [B*H][48][N]
    u16* xpre   = Vt + (size_t)3145728;                    // [ROWS][256]
    float* pcb  = (float*)(xpre + (size_t)2097152);        // [ROWS][8][3]
    float* G    = pcb + (size_t)ROWS * 24;                 // [24][64]
    // total ws use ~28.6 MB

    prep_k<<<3110, 256, 0, stream>>>(x1, x2, Wq, Wkv, Wproj, cor, Wcor, Wm,
                                     x1b, x2b, Wqt, Wkvt, Wprojt, Vt, G);
    gemm_k<0><<<dim3(128, 4), 256, 0, stream>>>(x1b, Wqt, Qh, nullptr, nullptr, nullptr);
    gemm_k<1><<<dim3(128, 8), 256, 0, stream>>>(x2b, Wkvt, Kh, Vt, nullptr, nullptr);
    attn_k<<<dim3(16, 32), 256, 0, stream>>>(Qh, Kh, Vt, xpre, pcb);
    gemm_k<2><<<dim3(128, 4), 256, 0, stream>>>(xpre, Wprojt, nullptr, nullptr, out_x, bproj);
    motion_k<<<ROWS / 4, 256, 0, stream>>>(pcb, cor, G, bm, out_motion);
}